// Round 10
// baseline (523.554 us; speedup 1.0000x reference)
//
#include <hip/hip_runtime.h>

typedef unsigned short u16;
typedef unsigned int u32;
typedef __attribute__((ext_vector_type(8))) short short8;   // 8 bf16 (4 VGPRs)
typedef __attribute__((ext_vector_type(4))) float f32x4;

struct __align__(8) us4 { u16 x, y, z, w; };

__device__ __forceinline__ float bf1(u16 v){ return __uint_as_float(((u32)v) << 16); }
__device__ __forceinline__ float bflo(u32 u){ return __uint_as_float(u << 16); }
__device__ __forceinline__ float bfhi(u32 u){ return __uint_as_float(u & 0xFFFF0000u); }
__device__ __forceinline__ u16 fbf(float f){
    u32 u = __float_as_uint(f);
    return (u16)((u + 0x7FFFu + ((u >> 16) & 1u)) >> 16);   // RTNE
}
__device__ __forceinline__ float gelu_exact(float x){
    return 0.5f * x * (1.0f + erff(x * 0.70710678118654752f));
}
__device__ __forceinline__ void unp8(uint4 u, float* f){
    f[0]=bflo(u.x); f[1]=bfhi(u.x); f[2]=bflo(u.y); f[3]=bfhi(u.y);
    f[4]=bflo(u.z); f[5]=bfhi(u.z); f[6]=bflo(u.w); f[7]=bfhi(u.w);
}
__device__ __forceinline__ uint4 pack8(float4 a, float4 b){
    uint4 u;
    u.x = (u32)fbf(a.x) | ((u32)fbf(a.y) << 16);
    u.y = (u32)fbf(a.z) | ((u32)fbf(a.w) << 16);
    u.z = (u32)fbf(b.x) | ((u32)fbf(b.y) << 16);
    u.w = (u32)fbf(b.z) | ((u32)fbf(b.w) << 16);
    return u;
}

#define MFMA16(a, b, c) __builtin_amdgcn_mfma_f32_16x16x32_bf16(a, b, c, 0, 0, 0)
#define QSTR 264
#define CAPROWS 47232   // >= 23 + 47104 worst case (fixes R8 latent bound)
#define H1STR 392       // h1 LDS tile stride (784 B rows: 16B-aligned, bank-offset)

// ---------------------------------------------------------------------------
// ws layout (bytes) — total 25,883,656 (well under proven 61,616,644):
//  0          : redb [CAPROWS][256] bf16 (24,182,784)  compact h2 pre-LN
//  24182784   : Wb   bf16 weights (661,760 elems = 1,323,520 B)
//  25506304   : idx  [47104] int
//  25694720   : rowsrc [CAPROWS] int
//  25883648   : cnt (int)
//  25883652   : lossAcc (f32)
// Compact slots 0..22 = canonical missing rows; 23.. = existing rows.
// ---------------------------------------------------------------------------

__global__ __launch_bounds__(256) void wconv(
    const float* __restrict__ W1, const float* __restrict__ W2,
    const float* __restrict__ Wq, const float* __restrict__ Wk,
    const float* __restrict__ Wv, const float* __restrict__ Wo,
    const float* __restrict__ Wp, u16* __restrict__ dst)
{
    const int i = blockIdx.x * 256 + threadIdx.x;   // grid exactly 661760
    const float* s; int o;
    if      (i < 294912) { s = W1; o = i; }
    else if (i < 393216) { s = W2; o = i - 294912; }
    else if (i < 458752) { s = Wq; o = i - 393216; }
    else if (i < 524288) { s = Wk; o = i - 458752; }
    else if (i < 589824) { s = Wv; o = i - 524288; }
    else if (i < 655360) { s = Wo; o = i - 589824; }
    else                 { s = Wp; o = i - 655360; }
    dst[i] = fbf(s[o]);
}

// ---- row compaction: existing rows -> slots 23.., missing table -> 0..22 ----
__global__ __launch_bounds__(256) void scan_kernel(
    const int* __restrict__ mask, int* __restrict__ idx,
    int* __restrict__ rowsrc, int* __restrict__ cnt)
{
    const int i = blockIdx.x * 256 + threadIdx.x;   // grid 184*256 = 47104
    if (blockIdx.x == 0 && threadIdx.x < 23)
        rowsrc[threadIdx.x] = -(threadIdx.x + 1);
    if (mask[i] > 0) {
        const int slot = 23 + atomicAdd(cnt, 1);    // wave-aggregated by compiler
        idx[i] = slot;
        rowsrc[slot] = i;
    }
}

// ---------------------------------------------------------------------------
// mlp_fused (R10): per 64-row block, h1[64][384] entirely in AGPRs
// (3 col-tiles x acc[2][4] = 96 AGPR; A staged ONCE per k-step, shared by all
// 3 tiles) -> gelu/bf16 into LDS h1t (As aliases its head: As dead before h1t
// written) -> h2[64][256] = gelu(h1t @ W2^T + b2) straight from LDS (no
// barriers in phase-2 k-loop) -> redb. Replaces gemm1 + gemm_bt; h1b global
// round-trip (36 MB write + 72 MB read) deleted. LDS 50176 B -> 3 blocks/CU.
// Bit-exact vs the 2-kernel path (same k-order, fragments, rounding points).
// ---------------------------------------------------------------------------
__global__ __launch_bounds__(256) void mlp_fused(
    const float* __restrict__ cls, const int* __restrict__ rowsrc,
    const int* __restrict__ cnt, const float* __restrict__ missing,
    const u16* __restrict__ W1b, const float* __restrict__ b1,
    const u16* __restrict__ W2b, const float* __restrict__ b2,
    u16* __restrict__ redb)
{
    const int nBase = blockIdx.x * 64;
    if (nBase >= *cnt + 23) return;                 // past compact rows
    __shared__ __align__(16) u16 h1t[64 * H1STR];   // 50176 B
    u16* As = h1t;                                  // [64][40] alias (phase-1 only)

    const int tid = threadIdx.x;
    const int w = tid >> 6, lane = tid & 63;
    const int wr = w >> 1, wc = w & 1;              // 2x2 waves over 32-row x 64-col
    const int r0 = tid >> 2;                        // 0..63
    const int co = (tid & 3) * 8;                   // 0,8,16,24
    const int frow = lane & 15, quad = lane >> 4;
    const f32x4 z4 = f32x4{0.f, 0.f, 0.f, 0.f};

    const int rs0 = rowsrc[nBase + r0];
    const float* ap0 = (rs0 >= 0) ? cls + (size_t)rs0 * 768
                                  : missing + (size_t)(-rs0 - 1) * 768;

    // ---- phase 1: h1 = gelu(sec @ W1^T + b1), 3 col-tiles in AGPRs ----
    f32x4 acc[3][2][4];
#pragma unroll
    for (int mtile = 0; mtile < 3; ++mtile)
#pragma unroll
        for (int mt = 0; mt < 2; ++mt)
#pragma unroll
            for (int nt = 0; nt < 4; ++nt) acc[mtile][mt][nt] = z4;

    float4 a0a = *(const float4*)(ap0 + co), a0b = *(const float4*)(ap0 + co + 4);

    for (int k0 = 0; k0 < 768; k0 += 32) {
        __syncthreads();
        *(uint4*)(As + r0 * 40 + co) = pack8(a0a, a0b);
        __syncthreads();
        if (k0 + 32 < 768) {
            const int kn = k0 + 32 + co;
            a0a = *(const float4*)(ap0 + kn); a0b = *(const float4*)(ap0 + kn + 4);
        }
        short8 a0 = *(const short8*)(As + (wr * 32 + frow) * 40 + quad * 8);
        short8 a1 = *(const short8*)(As + (wr * 32 + 16 + frow) * 40 + quad * 8);
#pragma unroll
        for (int mtile = 0; mtile < 3; ++mtile)
#pragma unroll
            for (int nt = 0; nt < 4; ++nt) {
                const int n = mtile * 128 + wc * 64 + nt * 16 + frow;
                short8 bfr = *(const short8*)(W1b + (size_t)n * 768 + k0 + quad * 8);
                acc[mtile][0][nt] = MFMA16(a0, bfr, acc[mtile][0][nt]);
                acc[mtile][1][nt] = MFMA16(a1, bfr, acc[mtile][1][nt]);
            }
    }
    __syncthreads();   // all As reads done -> h1t may overlay

    // epilogue 1: h1t = gelu(acc + b1), bf16
#pragma unroll
    for (int mtile = 0; mtile < 3; ++mtile)
#pragma unroll
        for (int nt = 0; nt < 4; ++nt) {
            const int col = mtile * 128 + wc * 64 + nt * 16 + frow;
            const float bv = b1[col];
#pragma unroll
            for (int mt = 0; mt < 2; ++mt)
#pragma unroll
                for (int reg = 0; reg < 4; ++reg) {
                    const int row = wr * 32 + mt * 16 + quad * 4 + reg;
                    h1t[row * H1STR + col] = fbf(gelu_exact(acc[mtile][mt][nt][reg] + bv));
                }
        }
    __syncthreads();   // h1t complete

    // ---- phase 2: h2 = gelu(h1t @ W2^T + b2) -> redb (no in-loop barriers) ----
    f32x4 acc2[2][2][4];
#pragma unroll
    for (int mt2 = 0; mt2 < 2; ++mt2)
#pragma unroll
        for (int mt = 0; mt < 2; ++mt)
#pragma unroll
            for (int nt = 0; nt < 4; ++nt) acc2[mt2][mt][nt] = z4;

    for (int k0 = 0; k0 < 384; k0 += 32) {
        short8 a0 = *(const short8*)(h1t + (wr * 32 + frow) * H1STR + k0 + quad * 8);
        short8 a1 = *(const short8*)(h1t + (wr * 32 + 16 + frow) * H1STR + k0 + quad * 8);
#pragma unroll
        for (int mt2 = 0; mt2 < 2; ++mt2)
#pragma unroll
            for (int nt = 0; nt < 4; ++nt) {
                const int n = mt2 * 128 + wc * 64 + nt * 16 + frow;
                short8 bfr = *(const short8*)(W2b + (size_t)n * 384 + k0 + quad * 8);
                acc2[mt2][0][nt] = MFMA16(a0, bfr, acc2[mt2][0][nt]);
                acc2[mt2][1][nt] = MFMA16(a1, bfr, acc2[mt2][1][nt]);
            }
    }

#pragma unroll
    for (int mt2 = 0; mt2 < 2; ++mt2)
#pragma unroll
        for (int nt = 0; nt < 4; ++nt) {
            const int col = mt2 * 128 + wc * 64 + nt * 16 + frow;
            const float bv = b2[col];
#pragma unroll
            for (int mt = 0; mt < 2; ++mt)
#pragma unroll
                for (int reg = 0; reg < 4; ++reg) {
                    const int row = nBase + wr * 32 + mt * 16 + quad * 4 + reg;
                    redb[(size_t)row * 256 + col] = fbf(gelu_exact(acc2[mt2][mt][nt][reg] + bv));
                }
        }
}

// ---- in-register LN: thread holds 8 cols of a row; the row's 32 cols-owners
// are one contiguous 32-lane group -> stats via shfl_xor {1,2,4,8,16}. ----
__device__ __forceinline__ void ln1_reg(
    const float* x, const float4& g0, const float4& g1,
    const float4& b0, const float4& b1, u16* rp)
{
    float s = x[0] + x[1] + x[2] + x[3] + x[4] + x[5] + x[6] + x[7];
    s += __shfl_xor(s, 1); s += __shfl_xor(s, 2); s += __shfl_xor(s, 4);
    s += __shfl_xor(s, 8); s += __shfl_xor(s, 16);
    const float mu = s * (1.f / 256.f);
    float v = 0.f;
#pragma unroll
    for (int e = 0; e < 8; ++e) { const float d = x[e] - mu; v += d * d; }
    v += __shfl_xor(v, 1); v += __shfl_xor(v, 2); v += __shfl_xor(v, 4);
    v += __shfl_xor(v, 8); v += __shfl_xor(v, 16);
    const float rs = rsqrtf(v * (1.f / 256.f) + 1e-5f);
    float4 ya, yb;
    ya.x = (x[0]-mu)*rs*g0.x + b0.x;
    ya.y = (x[1]-mu)*rs*g0.y + b0.y;
    ya.z = (x[2]-mu)*rs*g0.z + b0.z;
    ya.w = (x[3]-mu)*rs*g0.w + b0.w;
    yb.x = (x[4]-mu)*rs*g1.x + b1.x;
    yb.y = (x[5]-mu)*rs*g1.y + b1.y;
    yb.z = (x[6]-mu)*rs*g1.z + b1.z;
    yb.w = (x[7]-mu)*rs*g1.w + b1.w;
    *(uint4*)rp = pack8(ya, yb);
}

__device__ __forceinline__ void ln3_reg_store(
    uint4 rg0, uint4 rg1, uint4 rg2, bool has2,
    const float* __restrict__ lng, const float* __restrict__ lnb,
    u16* dstBase, int s0, int c0o)
{
    const float4 g0 = *(const float4*)(lng + c0o);
    const float4 g1 = *(const float4*)(lng + c0o + 4);
    const float4 b0 = *(const float4*)(lnb + c0o);
    const float4 b1 = *(const float4*)(lnb + c0o + 4);
    float x[8];
    unp8(rg0, x); ln1_reg(x, g0, g1, b0, b1, dstBase + s0 * QSTR + c0o);
    unp8(rg1, x); ln1_reg(x, g0, g1, b0, b1, dstBase + (s0 + 8) * QSTR + c0o);
    if (has2) { unp8(rg2, x); ln1_reg(x, g0, g1, b0, b1, dstBase + (s0 + 16) * QSTR + c0o); }
}

// ---- 8-step MFMA k-loop with 1-step software prefetch of the 4 global
// B-fragments ----
#define KLOOP_PF(WPTR, SRC, ACC)                                                  \
    {                                                                             \
        short8 nb0 = *(const short8*)(WPTR);                                      \
        short8 nb1 = *(const short8*)((WPTR) + 16 * 256);                         \
        short8 nb2 = *(const short8*)((WPTR) + 32 * 256);                         \
        short8 nb3 = *(const short8*)((WPTR) + 48 * 256);                         \
        for (int k0 = 0; k0 < 256; k0 += 32) {                                    \
            short8 a0 = *(const short8*)((SRC) + r0c * QSTR + k0 + quad * 8);     \
            short8 a1 = *(const short8*)((SRC) + r1c * QSTR + k0 + quad * 8);     \
            short8 c0 = nb0, c1 = nb1, c2 = nb2, c3 = nb3;                        \
            if (k0 + 32 < 256) {                                                  \
                nb0 = *(const short8*)((WPTR) + (k0 + 32));                       \
                nb1 = *(const short8*)((WPTR) + 16 * 256 + (k0 + 32));            \
                nb2 = *(const short8*)((WPTR) + 32 * 256 + (k0 + 32));            \
                nb3 = *(const short8*)((WPTR) + 48 * 256 + (k0 + 32));            \
            }                                                                     \
            ACC[0][0] = MFMA16(a0, c0, ACC[0][0]); ACC[1][0] = MFMA16(a1, c0, ACC[1][0]); \
            ACC[0][1] = MFMA16(a0, c1, ACC[0][1]); ACC[1][1] = MFMA16(a1, c1, ACC[1][1]); \
            ACC[0][2] = MFMA16(a0, c2, ACC[0][2]); ACC[1][2] = MFMA16(a1, c2, ACC[1][2]); \
            ACC[0][3] = MFMA16(a0, c3, ACC[0][3]); ACC[1][3] = MFMA16(a1, c3, ACC[1][3]); \
        }                                                                         \
    }

// ---------------------------------------------------------------------------
// attn_tail: R9-proven structure (183 µs, no spill), compact-row indirection.
// ---------------------------------------------------------------------------
__global__ __launch_bounds__(256, 3) void attn_tail_kernel(
    const u16* __restrict__ redb, const int* __restrict__ mask,
    const int* __restrict__ idxArr,
    const u16* __restrict__ Wqkvb,                       // [768][256]: q,k,v stacked
    const float* __restrict__ bq, const float* __restrict__ bk,
    const float* __restrict__ bv, const u16* __restrict__ Wob,
    const float* __restrict__ bo, const float* __restrict__ lng,
    const float* __restrict__ lnb, const u16* __restrict__ Wpb,
    const float* __restrict__ bp, float* __restrict__ out,
    float* __restrict__ lossAcc)
{
    __shared__ __align__(16) unsigned char SM[40960];
    u16* s_rq = (u16*)SM;                  // [23][264] red -> q -> ctx
    u16* s_k  = (u16*)(SM + 12144);        // [23][264] k -> P -> updated
    u16* s_vT = (u16*)(SM + 24288);        // [256][32] V^T, j>=23 zero
    int* sEx   = (int*)(SM + 40672);       // [23]
    int* sMiss = (int*)(SM + 40764);       // [23]
    int* sCrow = (int*)(SM + 40856);       // [23] compact row per slot
    // tail scratch aliases the dead s_vT region:
    float* sDiag = (float*)(SM + 24288);   // [23] gram diagonal
    float* sInv  = (float*)(SM + 24384);   // [23]
    float* sPool = (float*)(SM + 24480);   // [256]

    const int b = blockIdx.x, t = threadIdx.x;
    const int w = t >> 6, lane = t & 63;
    const int frow = lane & 15, quad = lane >> 4;
    const int r0c = frow;
    const int r1c = (16 + frow > 22) ? 22 : 16 + frow;   // clamp dup rows
    const f32x4 z4 = f32x4{0.f, 0.f, 0.f, 0.f};

    // mask -> sEx/sMiss/sCrow via wave-0 ballot
    {
        const int myEx = (t < 23) ? mask[b * 23 + t] : 0;
        if (t < 23) {
            sEx[t] = myEx;
            sCrow[t] = (myEx > 0) ? idxArr[b * 23 + t] : t;  // slot 0..22 = missing table
        }
        if (t < 64) {
            const unsigned long long ball = __ballot((t < 23) && (myEx > 0));
            if (t < 23) sMiss[t] = (ball != 0ull && myEx <= 0) ? 1 : 0;
        }
    }
    // zero s_vT (j>=23 K-pad for ctx MFMA): 16384 B = 1024 uint4
    for (int i = t; i < 1024; i += 256) ((uint4*)s_vT)[i] = make_uint4(0u, 0u, 0u, 0u);
    __syncthreads();   // sCrow ready for stage

    // stage h2 (compact rows) + in-register LN -> red directly into s_rq
    {
        const int s0 = t >> 5, c0o = (t & 31) * 8;
        uint4 rg0 = *(const uint4*)(redb + (size_t)sCrow[s0] * 256 + c0o);
        uint4 rg1 = *(const uint4*)(redb + (size_t)sCrow[s0 + 8] * 256 + c0o);
        uint4 rg2 = make_uint4(0u, 0u, 0u, 0u);
        const bool has2 = t < 224;
        if (has2) rg2 = *(const uint4*)(redb + (size_t)sCrow[s0 + 16] * 256 + c0o);
        ln3_reg_store(rg0, rg1, rg2, has2, lng, lnb, s_rq, s0, c0o);
    }
    __syncthreads();

    // ---- QKV in 3 pipelined passes (k, v, then q); wave w owns cols
    // [64w,64w+64) of each segment. ----
    const int cmb = w * 64 + frow;
    {   // k-pass
        f32x4 ka[2][4];
#pragma unroll
        for (int mt = 0; mt < 2; ++mt)
#pragma unroll
            for (int nt = 0; nt < 4; ++nt) ka[mt][nt] = z4;
        const u16* wp = Wqkvb + (size_t)(256 + cmb) * 256 + quad * 8;
        const float bb[4] = {bk[cmb], bk[cmb + 16], bk[cmb + 32], bk[cmb + 48]};
        KLOOP_PF(wp, s_rq, ka)
#pragma unroll
        for (int nt = 0; nt < 4; ++nt) {
            const int cm = cmb + nt * 16;
#pragma unroll
            for (int mt = 0; mt < 2; ++mt)
#pragma unroll
                for (int reg = 0; reg < 4; ++reg) {
                    const int s = mt * 16 + quad * 4 + reg;
                    if (s < 23) s_k[s * QSTR + cm] = fbf(ka[mt][nt][reg] + bb[nt]);
                }
        }
    }
    {   // v-pass (transposed store)
        f32x4 va[2][4];
#pragma unroll
        for (int mt = 0; mt < 2; ++mt)
#pragma unroll
            for (int nt = 0; nt < 4; ++nt) va[mt][nt] = z4;
        const u16* wp = Wqkvb + (size_t)(512 + cmb) * 256 + quad * 8;
        const float bb[4] = {bv[cmb], bv[cmb + 16], bv[cmb + 32], bv[cmb + 48]};
        KLOOP_PF(wp, s_rq, va)
#pragma unroll
        for (int nt = 0; nt < 4; ++nt) {
            const int cm = cmb + nt * 16;
#pragma unroll
            for (int mt = 0; mt < 2; ++mt)
#pragma unroll
                for (int reg = 0; reg < 4; ++reg) {
                    const int s = mt * 16 + quad * 4 + reg;
                    if (s < 23) s_vT[cm * 32 + s] = fbf(va[mt][nt][reg] + bb[nt]);
                }
        }
    }
    {   // q-pass: acc stays live across the barrier, then overlays red
        f32x4 qa[2][4];
#pragma unroll
        for (int mt = 0; mt < 2; ++mt)
#pragma unroll
            for (int nt = 0; nt < 4; ++nt) qa[mt][nt] = z4;
        const u16* wp = Wqkvb + (size_t)cmb * 256 + quad * 8;
        const float bb[4] = {bq[cmb], bq[cmb + 16], bq[cmb + 32], bq[cmb + 48]};
        KLOOP_PF(wp, s_rq, qa)
        __syncthreads();           // ALL waves done reading red
#pragma unroll
        for (int nt = 0; nt < 4; ++nt) {
            const int cm = cmb + nt * 16;
#pragma unroll
            for (int mt = 0; mt < 2; ++mt)
#pragma unroll
                for (int reg = 0; reg < 4; ++reg) {
                    const int s = mt * 16 + quad * 4 + reg;
                    if (s < 23) s_rq[s * QSTR + cm] = fbf(qa[mt][nt][reg] + bb[nt]);
                }
        }
    }
    // NO barrier: scores/ctx of wave w read only cols [64w,64w+64) it wrote.

    // ---- scores (MFMA) + softmax (shfl) + P write + ctx (MFMA), wave-private ----
    {
        const float scl = 0.17677669529663687f;       // 1/sqrt(32)
        const float m0 = (sEx[frow] > 0) ? 0.f : -1e9f;
        const float m1 = (16 + frow < 23 && sEx[16 + frow] > 0) ? 0.f : -1e9f;
#pragma unroll
        for (int hh2 = 0; hh2 < 2; ++hh2) {
            const int hb = w * 64 + hh2 * 32;
            short8 aq0 = *(const short8*)(s_rq + r0c * QSTR + hb + quad * 8);
            short8 aq1 = *(const short8*)(s_rq + r1c * QSTR + hb + quad * 8);
            short8 bk0 = *(const short8*)(s_k + r0c * QSTR + hb + quad * 8);
            short8 bk1 = *(const short8*)(s_k + r1c * QSTR + hb + quad * 8);
            f32x4 s00 = MFMA16(aq0, bk0, z4);
            f32x4 s01 = MFMA16(aq0, bk1, z4);
            f32x4 s10 = MFMA16(aq1, bk0, z4);
            f32x4 s11 = MFMA16(aq1, bk1, z4);
#pragma unroll
            for (int mt = 0; mt < 2; ++mt) {
                f32x4& c0 = mt ? s10 : s00;
                f32x4& c1 = mt ? s11 : s01;
#pragma unroll
                for (int reg = 0; reg < 4; ++reg) {
                    float v0 = c0[reg] * scl + m0;
                    float v1 = c1[reg] * scl + m1;
                    float mx = fmaxf(v0, v1);
#pragma unroll
                    for (int m = 8; m; m >>= 1) mx = fmaxf(mx, __shfl_xor(mx, m));
                    float p0 = __expf(v0 - mx), p1 = __expf(v1 - mx);
                    float sm = p0 + p1;
#pragma unroll
                    for (int m = 8; m; m >>= 1) sm += __shfl_xor(sm, m);
                    const float inv = 1.f / sm;
                    c0[reg] = p0 * inv;
                    c1[reg] = p1 * inv;
                }
            }
#pragma unroll
            for (int reg = 0; reg < 4; ++reg) {
                const int q0r = quad * 4 + reg;
                s_k[q0r * QSTR + hb + frow]      = fbf(s00[reg]);
                s_k[q0r * QSTR + hb + 16 + frow] = fbf(s01[reg]);
                const int q1r = 16 + quad * 4 + reg;
                if (q1r < 23) {
                    s_k[q1r * QSTR + hb + frow]      = fbf(s10[reg]);
                    s_k[q1r * QSTR + hb + 16 + frow] = fbf(s11[reg]);
                }
            }
            short8 pa0 = *(const short8*)(s_k + r0c * QSTR + hb + quad * 8);
            short8 pa1 = *(const short8*)(s_k + r1c * QSTR + hb + quad * 8);
            short8 bv0 = *(const short8*)(s_vT + (hb + frow) * 32 + quad * 8);
            short8 bv1 = *(const short8*)(s_vT + (hb + 16 + frow) * 32 + quad * 8);
            f32x4 c00 = MFMA16(pa0, bv0, z4);
            f32x4 c01 = MFMA16(pa0, bv1, z4);
            f32x4 c10 = MFMA16(pa1, bv0, z4);
            f32x4 c11 = MFMA16(pa1, bv1, z4);
#pragma unroll
            for (int reg = 0; reg < 4; ++reg) {
                const int q0r = quad * 4 + reg;
                s_rq[q0r * QSTR + hb + frow]      = fbf(c00[reg]);
                s_rq[q0r * QSTR + hb + 16 + frow] = fbf(c01[reg]);
                const int q1r = 16 + quad * 4 + reg;
                if (q1r < 23) {
                    s_rq[q1r * QSTR + hb + frow]      = fbf(c10[reg]);
                    s_rq[q1r * QSTR + hb + 16 + frow] = fbf(c11[reg]);
                }
            }
        }
    }
    __syncthreads();   // ctx (in s_rq) visible to all

    // ---- Wo (pipelined); THEN restage h2 (compact) + in-reg LN -> s_k ----
    {
        f32x4 wacc[2][4];
#pragma unroll
        for (int mt = 0; mt < 2; ++mt)
#pragma unroll
            for (int nt = 0; nt < 4; ++nt) wacc[mt][nt] = z4;
        const u16* wp = Wob + (size_t)cmb * 256 + quad * 8;
        const float ob[4] = {bo[cmb], bo[cmb + 16], bo[cmb + 32], bo[cmb + 48]};
        KLOOP_PF(wp, s_rq, wacc)
        // restage h2 (L2-hot) AFTER the k-loop
        {
            const int s0 = t >> 5, c0o = (t & 31) * 8;
            uint4 rg0 = *(const uint4*)(redb + (size_t)sCrow[s0] * 256 + c0o);
            uint4 rg1 = *(const uint4*)(redb + (size_t)sCrow[s0 + 8] * 256 + c0o);
            uint4 rg2 = make_uint4(0u, 0u, 0u, 0u);
            const bool has2 = t < 224;
            if (has2) rg2 = *(const uint4*)(redb + (size_t)sCrow[s0 + 16] * 256 + c0o);
            ln3_reg_store(rg0, rg1, rg2, has2, lng, lnb, s_k, s0, c0o);
        }
        __syncthreads();
        // missing rows: overwrite with mha_out = wacc + bo (own cols)
#pragma unroll
        for (int nt = 0; nt < 4; ++nt) {
            const int col = cmb + nt * 16;
#pragma unroll
            for (int mt = 0; mt < 2; ++mt)
#pragma unroll
                for (int reg = 0; reg < 4; ++reg) {
                    const int s = mt * 16 + quad * 4 + reg;
                    if (s < 23 && sMiss[s])
                        s_k[s * QSTR + col] = fbf(wacc[mt][nt][reg] + ob[nt]);
                }
        }
    }
    __syncthreads();   // s_k = updated [23][256]

    // ---- tail: gram via MFMA on wave 0 (diag = norms); pool on waves 1-3 ----
    f32x4 g00 = z4, g01 = z4, g10 = z4, g11 = z4;
    if (w == 0) {
        short8 ga0 = *(const short8*)(s_k + r0c * QSTR + quad * 8);
        short8 ga1 = *(const short8*)(s_k + r1c * QSTR + quad * 8);
        for (int k0 = 0; k0 < 256; k0 += 32) {
            short8 a0 = ga0, a1 = ga1;
            if (k0 + 32 < 256) {
                ga0 = *(const short8*)(s_k + r0c * QSTR + k0 + 32 + quad * 8);
                ga1 = *(const short8*)(s_k + r1c * QSTR + k0 + 32 + quad * 8);
            }
            g00 = MFMA16(a0, a0, g00);
            g01 = MFMA16(a0, a1, g01);
            g10 = MFMA16(a1, a0, g10);
            g11 = MFMA16(a1, a1, g11);
        }
#pragma unroll
        for (int reg = 0; reg < 4; ++reg) {
            if (frow == quad * 4 + reg) {
                sDiag[frow] = g00[reg];
                if (16 + frow < 23) sDiag[16 + frow] = g11[reg];
            }
        }
    } else {
        for (int c = t - 64; c < 256; c += 192) {
            float pv = 0.f;
#pragma unroll
            for (int s = 0; s < 23; ++s) pv += bf1(s_k[s * QSTR + c]);
            sPool[c] = pv * (1.f / 23.f);
        }
    }
    __syncthreads();
    if (t < 23) sInv[t] = 1.f / fmaxf(sqrtf(sDiag[t]), 1e-8f);
    __syncthreads();

    if (w == 0) {
        // margin loss from gram tiles (each ordered pair once)
        float contrib = 0.f;
        const float ic0 = sInv[frow];
        const float ic1 = (16 + frow < 23) ? sInv[16 + frow] : 0.f;
        const bool c1ok = (16 + frow < 23);
#pragma unroll
        for (int reg = 0; reg < 4; ++reg) {
            const int rA = quad * 4 + reg;          // < 16
            const float irA = sInv[rA];
            if (rA != frow) {
                const float cc = fabsf(g00[reg] * irA * ic0) - 0.1f;
                if (cc > 0.f) contrib += cc;
            }
            if (c1ok) {
                const float cc = fabsf(g01[reg] * irA * ic1) - 0.1f;
                if (cc > 0.f) contrib += cc;
            }
            const int rB = 16 + quad * 4 + reg;
            if (rB < 23) {
                const float irB = sInv[rB];
                {
                    const float cc = fabsf(g10[reg] * irB * ic0) - 0.1f;
                    if (cc > 0.f) contrib += cc;
                }
                if (c1ok && rB != 16 + frow) {
                    const float cc = fabsf(g11[reg] * irB * ic1) - 0.1f;
                    if (cc > 0.f) contrib += cc;
                }
            }
        }
#pragma unroll
        for (int m = 32; m; m >>= 1) contrib += __shfl_xor(contrib, m);
        if (lane == 0) atomicAdd(lossAcc, contrib);
    } else {
        // logits: labels 0..23 via 8 lanes/label on waves 1-3; label 24 on wave 1
        const int li = t - 64;
        {
            const int L = li >> 3, chunk = li & 7;
            float a = 0.f;
#pragma unroll
            for (int q4 = 0; q4 < 4; ++q4) {
                const int c8 = chunk * 4 + q4;
                float wf[8]; unp8(*(const uint4*)(Wpb + (size_t)L * 256 + c8 * 8), wf);
                const float4 p0 = *(const float4*)(sPool + c8 * 8);
                const float4 p1 = *(const float4*)(sPool + c8 * 8 + 4);
                a += wf[0] * p0.x + wf[1] * p0.y + wf[2] * p0.z + wf[3] * p0.w
                   + wf[4] * p1.x + wf[5] * p1.y + wf[6] * p1.z + wf[7] * p1.w;
            }
            a += __shfl_xor(a, 1); a += __shfl_xor(a, 2); a += __shfl_xor(a, 4);
            if (chunk == 0) out[1 + b * 25 + L] = a + bp[L];
        }
        if (li < 8) {
            float a = 0.f;
#pragma unroll
            for (int q4 = 0; q4 < 4; ++q4) {
                const int c8 = li * 4 + q4;
                float wf[8]; unp8(*(const uint4*)(Wpb + (size_t)24 * 256 + c8 * 8), wf);
                const float4 p0 = *(const float4*)(sPool + c8 * 8);
                const float4 p1 = *(const float4*)(sPool + c8 * 8 + 4);
                a += wf[0] * p0.x + wf[1] * p0.y + wf[2] * p0.z + wf[3] * p0.w
                   + wf[4] * p1.x + wf[5] * p1.y + wf[6] * p1.z + wf[7] * p1.w;
            }
            a += __shfl_xor(a, 1); a += __shfl_xor(a, 2); a += __shfl_xor(a, 4);
            if (li == 0) out[1 + b * 25 + 24] = a + bp[24];
        }
    }
}

__global__ void loss_finalize(const float* __restrict__ lossAcc, float* __restrict__ out)
{
    out[0] = lossAcc[0] * (1.f / 1036288.f);   // B*S*(S-1) = 2048*23*22
}

// ---------------------------------------------------------------------------
extern "C" void kernel_launch(void* const* d_in, const int* in_sizes, int n_in,
                              void* d_out, int out_size, void* d_ws, size_t ws_size,
                              hipStream_t stream)
{
    const float* cls     = (const float*)d_in[0];
    const int*   mask    = (const int*)d_in[1];
    const float* missing = (const float*)d_in[2];
    const float* W1 = (const float*)d_in[3];  const float* b1 = (const float*)d_in[4];
    const float* W2 = (const float*)d_in[5];  const float* b2 = (const float*)d_in[6];
    const float* lng = (const float*)d_in[7]; const float* lnb = (const float*)d_in[8];
    const float* Wq = (const float*)d_in[9];  const float* bq = (const float*)d_in[10];
    const float* Wk = (const float*)d_in[11]; const float* bk = (const float*)d_in[12];
    const float* Wv = (const float*)d_in[13]; const float* bv = (const float*)d_in[14];
    const float* Wo = (const float*)d_in[15]; const float* bo = (const float*)d_in[16];
    const float* Wp = (const float*)d_in[17]; const float* bp = (const float*)d_in[18];
    float* out = (float*)d_out;

    char* ws = (char*)d_ws;
    u16* redb = (u16*)ws;                         // [CAPROWS][256] compact h2
    u16* Wb   = (u16*)(ws + 24182784);            // bf16 weights (661,760 elems)
    u16* W1b   = Wb;
    u16* W2b   = Wb + 294912;
    u16* Wqkvb = Wb + 393216;                     // q,k,v contiguous [768][256]
    u16* Wob   = Wb + 589824;
    u16* Wpb   = Wb + 655360;
    int* idx    = (int*)(ws + 25506304);          // [47104]
    int* rowsrc = (int*)(ws + 25694720);          // [CAPROWS]
    int* cnt    = (int*)(ws + 25883648);
    float* lossAcc = (float*)(ws + 25883652);

    hipMemsetAsync(lossAcc, 0, sizeof(float), stream);
    hipMemsetAsync(cnt, 0, sizeof(int), stream);
    hipMemsetAsync(rowsrc, 0, CAPROWS * sizeof(int), stream);

    wconv<<<2585, 256, 0, stream>>>(W1, W2, Wq, Wk, Wv, Wo, Wp, Wb);
    // compact-row map: slots 0..22 = canonical missing rows, 23.. = existing
    scan_kernel<<<184, 256, 0, stream>>>(mask, idx, rowsrc, cnt);
    // fused MLP: h2[slot] = gelu(gelu(src @ W1^T + b1) @ W2^T + b2) -> redb
    mlp_fused<<<738, 256, 0, stream>>>(cls, rowsrc, cnt, missing,
                                       W1b, b1, W2b, b2, redb);
    // fused: LN + QKV + attention + Wo + updated + gram loss + pool + logits
    attn_tail_kernel<<<2048, 256, 0, stream>>>(redb, mask, idx, Wqkvb, bq, bk, bv,
                                               Wob, bo, lng, lnb, Wpb, bp,
                                               out, lossAcc);
    loss_finalize<<<1, 1, 0, stream>>>(lossAcc, out);
}

// Round 11
// 500.676 us; speedup vs baseline: 1.0457x; 1.0457x over previous
//
#include <hip/hip_runtime.h>

typedef unsigned short u16;
typedef unsigned int u32;
typedef __attribute__((ext_vector_type(8))) short short8;   // 8 bf16 (4 VGPRs)
typedef __attribute__((ext_vector_type(4))) float f32x4;

struct __align__(8) us4 { u16 x, y, z, w; };

__device__ __forceinline__ float bf1(u16 v){ return __uint_as_float(((u32)v) << 16); }
__device__ __forceinline__ float bflo(u32 u){ return __uint_as_float(u << 16); }
__device__ __forceinline__ float bfhi(u32 u){ return __uint_as_float(u & 0xFFFF0000u); }
__device__ __forceinline__ u16 fbf(float f){
    u32 u = __float_as_uint(f);
    return (u16)((u + 0x7FFFu + ((u >> 16) & 1u)) >> 16);   // RTNE
}
__device__ __forceinline__ float gelu_exact(float x){
    return 0.5f * x * (1.0f + erff(x * 0.70710678118654752f));
}
__device__ __forceinline__ void unp8(uint4 u, float* f){
    f[0]=bflo(u.x); f[1]=bfhi(u.x); f[2]=bflo(u.y); f[3]=bfhi(u.y);
    f[4]=bflo(u.z); f[5]=bfhi(u.z); f[6]=bflo(u.w); f[7]=bfhi(u.w);
}
__device__ __forceinline__ uint4 pack8(float4 a, float4 b){
    uint4 u;
    u.x = (u32)fbf(a.x) | ((u32)fbf(a.y) << 16);
    u.y = (u32)fbf(a.z) | ((u32)fbf(a.w) << 16);
    u.z = (u32)fbf(b.x) | ((u32)fbf(b.y) << 16);
    u.w = (u32)fbf(b.z) | ((u32)fbf(b.w) << 16);
    return u;
}

#define MFMA16(a, b, c) __builtin_amdgcn_mfma_f32_16x16x32_bf16(a, b, c, 0, 0, 0)
#define QSTR 264
#define CAPROWS 46208   // compact-row capacity (23 canonical missing + existing)

// ---------------------------------------------------------------------------
// ws layout (bytes) — total 60,843,016 (R9-proven):
//  0          : h1b  [CAPROWS][384] bf16  (35,487,744)   COMPACT rows
//  35487744   : redb [CAPROWS][256] bf16  (23,658,496)   COMPACT rows, h2 pre-LN
//  59146240   : Wb   bf16 weights (661,760 elems = 1,323,520 B)
//  60469760   : idx  [47104] int   (orig row -> compact slot, existing only)
//  60658176   : rowsrc [CAPROWS] int (compact slot -> orig row; -(s+1)=missing s)
//  60843008   : cnt (int)  — # existing rows
//  60843012   : lossAcc (f32)
// Compact slots 0..22 = canonical missing rows; 23.. = existing rows.
// ---------------------------------------------------------------------------

// wconv + fused row-compaction scan (R11): first 47104 threads also build the
// compact-row map (independent outputs; stream-ordered after memsets).
__global__ __launch_bounds__(256) void wconv(
    const float* __restrict__ W1, const float* __restrict__ W2,
    const float* __restrict__ Wq, const float* __restrict__ Wk,
    const float* __restrict__ Wv, const float* __restrict__ Wo,
    const float* __restrict__ Wp, u16* __restrict__ dst,
    const int* __restrict__ mask, int* __restrict__ idx,
    int* __restrict__ rowsrc, int* __restrict__ cnt)
{
    const int i = blockIdx.x * 256 + threadIdx.x;   // grid exactly 661760
    if (i < 47104) {
        if (i < 23) rowsrc[i] = -(i + 1);
        if (mask[i] > 0) {
            const int slot = 23 + atomicAdd(cnt, 1);    // wave-aggregated
            idx[i] = slot;
            rowsrc[slot] = i;
        }
    }
    const float* s; int o;
    if      (i < 294912) { s = W1; o = i; }
    else if (i < 393216) { s = W2; o = i - 294912; }
    else if (i < 458752) { s = Wq; o = i - 393216; }
    else if (i < 524288) { s = Wk; o = i - 458752; }
    else if (i < 589824) { s = Wv; o = i - 524288; }
    else if (i < 655360) { s = Wo; o = i - 589824; }
    else                 { s = Wp; o = i - 655360; }
    dst[i] = fbf(s[o]);
}

// ---------------------------------------------------------------------------
// GEMM1 (compact, fused gather): C[slot][384] = gelu(srcrow @ W1^T + b1).
// ---------------------------------------------------------------------------
__global__ __launch_bounds__(256) void gemm1_kernel(
    const float* __restrict__ cls, const int* __restrict__ rowsrc,
    const int* __restrict__ cnt, const float* __restrict__ missing,
    const u16* __restrict__ W, const float* __restrict__ bias,
    u16* __restrict__ C)
{
    const int K = 768, M = 384;
    const int nBase = blockIdx.y * 128;
    if (nBase >= *cnt + 23) return;                 // past compact rows
    __shared__ u16 As[128 * 40];
    __shared__ u16 Bs[128 * 40];
    const int tid = threadIdx.x;
    const int w = tid >> 6, lane = tid & 63;
    const int mBase = blockIdx.x * 128;
    const int wr = w >> 1, wc = w & 1;
    const int r0 = tid >> 2;
    const int co = (tid & 3) * 8;
    const int frow = lane & 15, quad = lane >> 4;

    const int rs0 = rowsrc[nBase + r0];
    const int rs1 = rowsrc[nBase + r0 + 64];
    const float* ap0 = (rs0 >= 0) ? cls + (size_t)rs0 * 768
                                  : missing + (size_t)(-rs0 - 1) * 768;
    const float* ap1 = (rs1 >= 0) ? cls + (size_t)rs1 * 768
                                  : missing + (size_t)(-rs1 - 1) * 768;
    const u16* bp0 = W + (size_t)(mBase + r0) * K;
    const u16* bp1 = W + (size_t)(mBase + r0 + 64) * K;

    f32x4 acc[4][4];
#pragma unroll
    for (int mt = 0; mt < 4; ++mt)
#pragma unroll
        for (int nt = 0; nt < 4; ++nt) acc[mt][nt] = f32x4{0.f, 0.f, 0.f, 0.f};

    float4 a0a = *(const float4*)(ap0 + co), a0b = *(const float4*)(ap0 + co + 4);
    float4 a1a = *(const float4*)(ap1 + co), a1b = *(const float4*)(ap1 + co + 4);
    uint4 pb0 = *(const uint4*)(bp0 + co), pb1 = *(const uint4*)(bp1 + co);

    for (int k0 = 0; k0 < K; k0 += 32) {
        __syncthreads();
        *(uint4*)(As + r0 * 40 + co) = pack8(a0a, a0b);
        *(uint4*)(As + (r0 + 64) * 40 + co) = pack8(a1a, a1b);
        *(uint4*)(Bs + r0 * 40 + co) = pb0;
        *(uint4*)(Bs + (r0 + 64) * 40 + co) = pb1;
        __syncthreads();
        if (k0 + 32 < K) {
            const int kn = k0 + 32 + co;
            a0a = *(const float4*)(ap0 + kn); a0b = *(const float4*)(ap0 + kn + 4);
            a1a = *(const float4*)(ap1 + kn); a1b = *(const float4*)(ap1 + kn + 4);
            pb0 = *(const uint4*)(bp0 + kn);  pb1 = *(const uint4*)(bp1 + kn);
        }
        short8 af[4], bfv[4];
#pragma unroll
        for (int mt = 0; mt < 4; ++mt)
            af[mt] = *(const short8*)(As + (wr * 64 + mt * 16 + frow) * 40 + quad * 8);
#pragma unroll
        for (int nt = 0; nt < 4; ++nt)
            bfv[nt] = *(const short8*)(Bs + (wc * 64 + nt * 16 + frow) * 40 + quad * 8);
#pragma unroll
        for (int mt = 0; mt < 4; ++mt)
#pragma unroll
            for (int nt = 0; nt < 4; ++nt)
                acc[mt][nt] = MFMA16(af[mt], bfv[nt], acc[mt][nt]);
    }

#pragma unroll
    for (int nt = 0; nt < 4; ++nt) {
        const int col = mBase + wc * 64 + nt * 16 + frow;
        const float bv = bias[col];
#pragma unroll
        for (int mt = 0; mt < 4; ++mt)
#pragma unroll
            for (int reg = 0; reg < 4; ++reg) {
                const int row = nBase + wr * 64 + mt * 16 + quad * 4 + reg;
                C[(size_t)row * M + col] = fbf(gelu_exact(acc[mt][nt][reg] + bv));
            }
    }
}

// ---------------------------------------------------------------------------
// GEMM2 (compact): C[N,M] bf16 = gelu(A @ W^T + bias), bf16 inputs.
// ---------------------------------------------------------------------------
__global__ __launch_bounds__(256) void gemm_bt(
    const u16* __restrict__ A, const u16* __restrict__ W,
    const float* __restrict__ bias, u16* __restrict__ C, int K, int M,
    const int* __restrict__ cnt)
{
    const int nBase = blockIdx.y * 128;
    if (nBase >= *cnt + 23) return;
    __shared__ u16 As[128 * 40];
    __shared__ u16 Bs[128 * 40];
    const int tid = threadIdx.x;
    const int w = tid >> 6, lane = tid & 63;
    const int mBase = blockIdx.x * 128;
    const int wr = w >> 1, wc = w & 1;
    const int r0 = tid >> 2;
    const int co = (tid & 3) * 8;
    const int frow = lane & 15, quad = lane >> 4;

    f32x4 acc[4][4];
#pragma unroll
    for (int mt = 0; mt < 4; ++mt)
#pragma unroll
        for (int nt = 0; nt < 4; ++nt) acc[mt][nt] = f32x4{0.f, 0.f, 0.f, 0.f};

    uint4 pa0 = *(const uint4*)(A + (size_t)(nBase + r0) * K + co);
    uint4 pa1 = *(const uint4*)(A + (size_t)(nBase + r0 + 64) * K + co);
    uint4 pb0 = *(const uint4*)(W + (size_t)(mBase + r0) * K + co);
    uint4 pb1 = *(const uint4*)(W + (size_t)(mBase + r0 + 64) * K + co);

    for (int k0 = 0; k0 < K; k0 += 32) {
        __syncthreads();
        *(uint4*)(As + r0 * 40 + co) = pa0;
        *(uint4*)(As + (r0 + 64) * 40 + co) = pa1;
        *(uint4*)(Bs + r0 * 40 + co) = pb0;
        *(uint4*)(Bs + (r0 + 64) * 40 + co) = pb1;
        __syncthreads();
        if (k0 + 32 < K) {
            const int kn = k0 + 32 + co;
            pa0 = *(const uint4*)(A + (size_t)(nBase + r0) * K + kn);
            pa1 = *(const uint4*)(A + (size_t)(nBase + r0 + 64) * K + kn);
            pb0 = *(const uint4*)(W + (size_t)(mBase + r0) * K + kn);
            pb1 = *(const uint4*)(W + (size_t)(mBase + r0 + 64) * K + kn);
        }
        short8 af[4], bfv[4];
#pragma unroll
        for (int mt = 0; mt < 4; ++mt)
            af[mt] = *(const short8*)(As + (wr * 64 + mt * 16 + frow) * 40 + quad * 8);
#pragma unroll
        for (int nt = 0; nt < 4; ++nt)
            bfv[nt] = *(const short8*)(Bs + (wc * 64 + nt * 16 + frow) * 40 + quad * 8);
#pragma unroll
        for (int mt = 0; mt < 4; ++mt)
#pragma unroll
            for (int nt = 0; nt < 4; ++nt)
                acc[mt][nt] = MFMA16(af[mt], bfv[nt], acc[mt][nt]);
    }

#pragma unroll
    for (int nt = 0; nt < 4; ++nt) {
        const int col = mBase + wc * 64 + nt * 16 + frow;
        const float bv = bias[col];
#pragma unroll
        for (int mt = 0; mt < 4; ++mt)
#pragma unroll
            for (int reg = 0; reg < 4; ++reg) {
                const int row = nBase + wr * 64 + mt * 16 + quad * 4 + reg;
                C[(size_t)row * M + col] = fbf(gelu_exact(acc[mt][nt][reg] + bv));
            }
    }
}

// ---- in-register LN: thread holds 8 cols of a row; the row's 32 cols-owners
// are one contiguous 32-lane group -> stats via shfl_xor {1,2,4,8,16}. ----
__device__ __forceinline__ void ln1_reg(
    const float* x, const float4& g0, const float4& g1,
    const float4& b0, const float4& b1, u16* rp)
{
    float s = x[0] + x[1] + x[2] + x[3] + x[4] + x[5] + x[6] + x[7];
    s += __shfl_xor(s, 1); s += __shfl_xor(s, 2); s += __shfl_xor(s, 4);
    s += __shfl_xor(s, 8); s += __shfl_xor(s, 16);
    const float mu = s * (1.f / 256.f);
    float v = 0.f;
#pragma unroll
    for (int e = 0; e < 8; ++e) { const float d = x[e] - mu; v += d * d; }
    v += __shfl_xor(v, 1); v += __shfl_xor(v, 2); v += __shfl_xor(v, 4);
    v += __shfl_xor(v, 8); v += __shfl_xor(v, 16);
    const float rs = rsqrtf(v * (1.f / 256.f) + 1e-5f);
    float4 ya, yb;
    ya.x = (x[0]-mu)*rs*g0.x + b0.x;
    ya.y = (x[1]-mu)*rs*g0.y + b0.y;
    ya.z = (x[2]-mu)*rs*g0.z + b0.z;
    ya.w = (x[3]-mu)*rs*g0.w + b0.w;
    yb.x = (x[4]-mu)*rs*g1.x + b1.x;
    yb.y = (x[5]-mu)*rs*g1.y + b1.y;
    yb.z = (x[6]-mu)*rs*g1.z + b1.z;
    yb.w = (x[7]-mu)*rs*g1.w + b1.w;
    *(uint4*)rp = pack8(ya, yb);
}

__device__ __forceinline__ void ln3_reg_store(
    uint4 rg0, uint4 rg1, uint4 rg2, bool has2,
    const float* __restrict__ lng, const float* __restrict__ lnb,
    u16* dstBase, int s0, int c0o)
{
    const float4 g0 = *(const float4*)(lng + c0o);
    const float4 g1 = *(const float4*)(lng + c0o + 4);
    const float4 b0 = *(const float4*)(lnb + c0o);
    const float4 b1 = *(const float4*)(lnb + c0o + 4);
    float x[8];
    unp8(rg0, x); ln1_reg(x, g0, g1, b0, b1, dstBase + s0 * QSTR + c0o);
    unp8(rg1, x); ln1_reg(x, g0, g1, b0, b1, dstBase + (s0 + 8) * QSTR + c0o);
    if (has2) { unp8(rg2, x); ln1_reg(x, g0, g1, b0, b1, dstBase + (s0 + 16) * QSTR + c0o); }
}

// ---- 8-step MFMA k-loop with 1-step software prefetch of the 4 global
// B-fragments ----
#define KLOOP_PF(WPTR, SRC, ACC)                                                  \
    {                                                                             \
        short8 nb0 = *(const short8*)(WPTR);                                      \
        short8 nb1 = *(const short8*)((WPTR) + 16 * 256);                         \
        short8 nb2 = *(const short8*)((WPTR) + 32 * 256);                         \
        short8 nb3 = *(const short8*)((WPTR) + 48 * 256);                         \
        for (int k0 = 0; k0 < 256; k0 += 32) {                                    \
            short8 a0 = *(const short8*)((SRC) + r0c * QSTR + k0 + quad * 8);     \
            short8 a1 = *(const short8*)((SRC) + r1c * QSTR + k0 + quad * 8);     \
            short8 c0 = nb0, c1 = nb1, c2 = nb2, c3 = nb3;                        \
            if (k0 + 32 < 256) {                                                  \
                nb0 = *(const short8*)((WPTR) + (k0 + 32));                       \
                nb1 = *(const short8*)((WPTR) + 16 * 256 + (k0 + 32));            \
                nb2 = *(const short8*)((WPTR) + 32 * 256 + (k0 + 32));            \
                nb3 = *(const short8*)((WPTR) + 48 * 256 + (k0 + 32));            \
            }                                                                     \
            ACC[0][0] = MFMA16(a0, c0, ACC[0][0]); ACC[1][0] = MFMA16(a1, c0, ACC[1][0]); \
            ACC[0][1] = MFMA16(a0, c1, ACC[0][1]); ACC[1][1] = MFMA16(a1, c1, ACC[1][1]); \
            ACC[0][2] = MFMA16(a0, c2, ACC[0][2]); ACC[1][2] = MFMA16(a1, c2, ACC[1][2]); \
            ACC[0][3] = MFMA16(a0, c3, ACC[0][3]); ACC[1][3] = MFMA16(a1, c3, ACC[1][3]); \
        }                                                                         \
    }

// ---------------------------------------------------------------------------
// attn_tail: R9-proven structure (183 µs, no spill), compact-row indirection.
// ---------------------------------------------------------------------------
__global__ __launch_bounds__(256, 3) void attn_tail_kernel(
    const u16* __restrict__ redb, const int* __restrict__ mask,
    const int* __restrict__ idxArr,
    const u16* __restrict__ Wqkvb,                       // [768][256]: q,k,v stacked
    const float* __restrict__ bq, const float* __restrict__ bk,
    const float* __restrict__ bv, const u16* __restrict__ Wob,
    const float* __restrict__ bo, const float* __restrict__ lng,
    const float* __restrict__ lnb, const u16* __restrict__ Wpb,
    const float* __restrict__ bp, float* __restrict__ out,
    float* __restrict__ lossAcc)
{
    __shared__ __align__(16) unsigned char SM[40960];
    u16* s_rq = (u16*)SM;                  // [23][264] red -> q -> ctx
    u16* s_k  = (u16*)(SM + 12144);        // [23][264] k -> P -> updated
    u16* s_vT = (u16*)(SM + 24288);        // [256][32] V^T, j>=23 zero
    int* sEx   = (int*)(SM + 40672);       // [23]
    int* sMiss = (int*)(SM + 40764);       // [23]
    int* sCrow = (int*)(SM + 40856);       // [23] compact row per slot
    // tail scratch aliases the dead s_vT region:
    float* sDiag = (float*)(SM + 24288);   // [23] gram diagonal
    float* sInv  = (float*)(SM + 24384);   // [23]
    float* sPool = (float*)(SM + 24480);   // [256]

    const int b = blockIdx.x, t = threadIdx.x;
    const int w = t >> 6, lane = t & 63;
    const int frow = lane & 15, quad = lane >> 4;
    const int r0c = frow;
    const int r1c = (16 + frow > 22) ? 22 : 16 + frow;   // clamp dup rows
    const f32x4 z4 = f32x4{0.f, 0.f, 0.f, 0.f};

    // mask -> sEx/sMiss/sCrow via wave-0 ballot
    {
        const int myEx = (t < 23) ? mask[b * 23 + t] : 0;
        if (t < 23) {
            sEx[t] = myEx;
            sCrow[t] = (myEx > 0) ? idxArr[b * 23 + t] : t;  // slot 0..22 = missing table
        }
        if (t < 64) {
            const unsigned long long ball = __ballot((t < 23) && (myEx > 0));
            if (t < 23) sMiss[t] = (ball != 0ull && myEx <= 0) ? 1 : 0;
        }
    }
    // zero s_vT (j>=23 K-pad for ctx MFMA): 16384 B = 1024 uint4
    for (int i = t; i < 1024; i += 256) ((uint4*)s_vT)[i] = make_uint4(0u, 0u, 0u, 0u);
    __syncthreads();   // sCrow ready for stage

    // stage h2 (compact rows) + in-register LN -> red directly into s_rq
    {
        const int s0 = t >> 5, c0o = (t & 31) * 8;
        uint4 rg0 = *(const uint4*)(redb + (size_t)sCrow[s0] * 256 + c0o);
        uint4 rg1 = *(const uint4*)(redb + (size_t)sCrow[s0 + 8] * 256 + c0o);
        uint4 rg2 = make_uint4(0u, 0u, 0u, 0u);
        const bool has2 = t < 224;
        if (has2) rg2 = *(const uint4*)(redb + (size_t)sCrow[s0 + 16] * 256 + c0o);
        ln3_reg_store(rg0, rg1, rg2, has2, lng, lnb, s_rq, s0, c0o);
    }
    __syncthreads();

    // ---- QKV in 3 pipelined passes (k, v, then q); wave w owns cols
    // [64w,64w+64) of each segment. ----
    const int cmb = w * 64 + frow;
    {   // k-pass
        f32x4 ka[2][4];
#pragma unroll
        for (int mt = 0; mt < 2; ++mt)
#pragma unroll
            for (int nt = 0; nt < 4; ++nt) ka[mt][nt] = z4;
        const u16* wp = Wqkvb + (size_t)(256 + cmb) * 256 + quad * 8;
        const float bb[4] = {bk[cmb], bk[cmb + 16], bk[cmb + 32], bk[cmb + 48]};
        KLOOP_PF(wp, s_rq, ka)
#pragma unroll
        for (int nt = 0; nt < 4; ++nt) {
            const int cm = cmb + nt * 16;
#pragma unroll
            for (int mt = 0; mt < 2; ++mt)
#pragma unroll
                for (int reg = 0; reg < 4; ++reg) {
                    const int s = mt * 16 + quad * 4 + reg;
                    if (s < 23) s_k[s * QSTR + cm] = fbf(ka[mt][nt][reg] + bb[nt]);
                }
        }
    }
    {   // v-pass (transposed store)
        f32x4 va[2][4];
#pragma unroll
        for (int mt = 0; mt < 2; ++mt)
#pragma unroll
            for (int nt = 0; nt < 4; ++nt) va[mt][nt] = z4;
        const u16* wp = Wqkvb + (size_t)(512 + cmb) * 256 + quad * 8;
        const float bb[4] = {bv[cmb], bv[cmb + 16], bv[cmb + 32], bv[cmb + 48]};
        KLOOP_PF(wp, s_rq, va)
#pragma unroll
        for (int nt = 0; nt < 4; ++nt) {
            const int cm = cmb + nt * 16;
#pragma unroll
            for (int mt = 0; mt < 2; ++mt)
#pragma unroll
                for (int reg = 0; reg < 4; ++reg) {
                    const int s = mt * 16 + quad * 4 + reg;
                    if (s < 23) s_vT[cm * 32 + s] = fbf(va[mt][nt][reg] + bb[nt]);
                }
        }
    }
    {   // q-pass: acc stays live across the barrier, then overlays red
        f32x4 qa[2][4];
#pragma unroll
        for (int mt = 0; mt < 2; ++mt)
#pragma unroll
            for (int nt = 0; nt < 4; ++nt) qa[mt][nt] = z4;
        const u16* wp = Wqkvb + (size_t)cmb * 256 + quad * 8;
        const float bb[4] = {bq[cmb], bq[cmb + 16], bq[cmb + 32], bq[cmb + 48]};
        KLOOP_PF(wp, s_rq, qa)
        __syncthreads();           // ALL waves done reading red
#pragma unroll
        for (int nt = 0; nt < 4; ++nt) {
            const int cm = cmb + nt * 16;
#pragma unroll
            for (int mt = 0; mt < 2; ++mt)
#pragma unroll
                for (int reg = 0; reg < 4; ++reg) {
                    const int s = mt * 16 + quad * 4 + reg;
                    if (s < 23) s_rq[s * QSTR + cm] = fbf(qa[mt][nt][reg] + bb[nt]);
                }
        }
    }
    // NO barrier: scores/ctx of wave w read only cols [64w,64w+64) it wrote.

    // ---- scores (MFMA) + softmax (shfl) + P write + ctx (MFMA), wave-private ----
    {
        const float scl = 0.17677669529663687f;       // 1/sqrt(32)
        const float m0 = (sEx[frow] > 0) ? 0.f : -1e9f;
        const float m1 = (16 + frow < 23 && sEx[16 + frow] > 0) ? 0.f : -1e9f;
#pragma unroll
        for (int hh2 = 0; hh2 < 2; ++hh2) {
            const int hb = w * 64 + hh2 * 32;
            short8 aq0 = *(const short8*)(s_rq + r0c * QSTR + hb + quad * 8);
            short8 aq1 = *(const short8*)(s_rq + r1c * QSTR + hb + quad * 8);
            short8 bk0 = *(const short8*)(s_k + r0c * QSTR + hb + quad * 8);
            short8 bk1 = *(const short8*)(s_k + r1c * QSTR + hb + quad * 8);
            f32x4 s00 = MFMA16(aq0, bk0, z4);
            f32x4 s01 = MFMA16(aq0, bk1, z4);
            f32x4 s10 = MFMA16(aq1, bk0, z4);
            f32x4 s11 = MFMA16(aq1, bk1, z4);
#pragma unroll
            for (int mt = 0; mt < 2; ++mt) {
                f32x4& c0 = mt ? s10 : s00;
                f32x4& c1 = mt ? s11 : s01;
#pragma unroll
                for (int reg = 0; reg < 4; ++reg) {
                    float v0 = c0[reg] * scl + m0;
                    float v1 = c1[reg] * scl + m1;
                    float mx = fmaxf(v0, v1);
#pragma unroll
                    for (int m = 8; m; m >>= 1) mx = fmaxf(mx, __shfl_xor(mx, m));
                    float p0 = __expf(v0 - mx), p1 = __expf(v1 - mx);
                    float sm = p0 + p1;
#pragma unroll
                    for (int m = 8; m; m >>= 1) sm += __shfl_xor(sm, m);
                    const float inv = 1.f / sm;
                    c0[reg] = p0 * inv;
                    c1[reg] = p1 * inv;
                }
            }
#pragma unroll
            for (int reg = 0; reg < 4; ++reg) {
                const int q0r = quad * 4 + reg;
                s_k[q0r * QSTR + hb + frow]      = fbf(s00[reg]);
                s_k[q0r * QSTR + hb + 16 + frow] = fbf(s01[reg]);
                const int q1r = 16 + quad * 4 + reg;
                if (q1r < 23) {
                    s_k[q1r * QSTR + hb + frow]      = fbf(s10[reg]);
                    s_k[q1r * QSTR + hb + 16 + frow] = fbf(s11[reg]);
                }
            }
            short8 pa0 = *(const short8*)(s_k + r0c * QSTR + hb + quad * 8);
            short8 pa1 = *(const short8*)(s_k + r1c * QSTR + hb + quad * 8);
            short8 bv0 = *(const short8*)(s_vT + (hb + frow) * 32 + quad * 8);
            short8 bv1 = *(const short8*)(s_vT + (hb + 16 + frow) * 32 + quad * 8);
            f32x4 c00 = MFMA16(pa0, bv0, z4);
            f32x4 c01 = MFMA16(pa0, bv1, z4);
            f32x4 c10 = MFMA16(pa1, bv0, z4);
            f32x4 c11 = MFMA16(pa1, bv1, z4);
#pragma unroll
            for (int reg = 0; reg < 4; ++reg) {
                const int q0r = quad * 4 + reg;
                s_rq[q0r * QSTR + hb + frow]      = fbf(c00[reg]);
                s_rq[q0r * QSTR + hb + 16 + frow] = fbf(c01[reg]);
                const int q1r = 16 + quad * 4 + reg;
                if (q1r < 23) {
                    s_rq[q1r * QSTR + hb + frow]      = fbf(c10[reg]);
                    s_rq[q1r * QSTR + hb + 16 + frow] = fbf(c11[reg]);
                }
            }
        }
    }
    __syncthreads();   // ctx (in s_rq) visible to all

    // ---- Wo (pipelined); THEN restage h2 (compact) + in-reg LN -> s_k ----
    {
        f32x4 wacc[2][4];
#pragma unroll
        for (int mt = 0; mt < 2; ++mt)
#pragma unroll
            for (int nt = 0; nt < 4; ++nt) wacc[mt][nt] = z4;
        const u16* wp = Wob + (size_t)cmb * 256 + quad * 8;
        const float ob[4] = {bo[cmb], bo[cmb + 16], bo[cmb + 32], bo[cmb + 48]};
        KLOOP_PF(wp, s_rq, wacc)
        // restage h2 (L2-hot) AFTER the k-loop
        {
            const int s0 = t >> 5, c0o = (t & 31) * 8;
            uint4 rg0 = *(const uint4*)(redb + (size_t)sCrow[s0] * 256 + c0o);
            uint4 rg1 = *(const uint4*)(redb + (size_t)sCrow[s0 + 8] * 256 + c0o);
            uint4 rg2 = make_uint4(0u, 0u, 0u, 0u);
            const bool has2 = t < 224;
            if (has2) rg2 = *(const uint4*)(redb + (size_t)sCrow[s0 + 16] * 256 + c0o);
            ln3_reg_store(rg0, rg1, rg2, has2, lng, lnb, s_k, s0, c0o);
        }
        __syncthreads();
        // missing rows: overwrite with mha_out = wacc + bo (own cols)
#pragma unroll
        for (int nt = 0; nt < 4; ++nt) {
            const int col = cmb + nt * 16;
#pragma unroll
            for (int mt = 0; mt < 2; ++mt)
#pragma unroll
                for (int reg = 0; reg < 4; ++reg) {
                    const int s = mt * 16 + quad * 4 + reg;
                    if (s < 23 && sMiss[s])
                        s_k[s * QSTR + col] = fbf(wacc[mt][nt][reg] + ob[nt]);
                }
        }
    }
    __syncthreads();   // s_k = updated [23][256]

    // ---- tail: gram via MFMA on wave 0 (diag = norms); pool on waves 1-3 ----
    f32x4 g00 = z4, g01 = z4, g10 = z4, g11 = z4;
    if (w == 0) {
        short8 ga0 = *(const short8*)(s_k + r0c * QSTR + quad * 8);
        short8 ga1 = *(const short8*)(s_k + r1c * QSTR + quad * 8);
        for (int k0 = 0; k0 < 256; k0 += 32) {
            short8 a0 = ga0, a1 = ga1;
            if (k0 + 32 < 256) {
                ga0 = *(const short8*)(s_k + r0c * QSTR + k0 + 32 + quad * 8);
                ga1 = *(const short8*)(s_k + r1c * QSTR + k0 + 32 + quad * 8);
            }
            g00 = MFMA16(a0, a0, g00);
            g01 = MFMA16(a0, a1, g01);
            g10 = MFMA16(a1, a0, g10);
            g11 = MFMA16(a1, a1, g11);
        }
#pragma unroll
        for (int reg = 0; reg < 4; ++reg) {
            if (frow == quad * 4 + reg) {
                sDiag[frow] = g00[reg];
                if (16 + frow < 23) sDiag[16 + frow] = g11[reg];
            }
        }
    } else {
        for (int c = t - 64; c < 256; c += 192) {
            float pv = 0.f;
#pragma unroll
            for (int s = 0; s < 23; ++s) pv += bf1(s_k[s * QSTR + c]);
            sPool[c] = pv * (1.f / 23.f);
        }
    }
    __syncthreads();
    if (t < 23) sInv[t] = 1.f / fmaxf(sqrtf(sDiag[t]), 1e-8f);
    __syncthreads();

    if (w == 0) {
        // margin loss from gram tiles (each ordered pair once)
        float contrib = 0.f;
        const float ic0 = sInv[frow];
        const float ic1 = (16 + frow < 23) ? sInv[16 + frow] : 0.f;
        const bool c1ok = (16 + frow < 23);
#pragma unroll
        for (int reg = 0; reg < 4; ++reg) {
            const int rA = quad * 4 + reg;          // < 16
            const float irA = sInv[rA];
            if (rA != frow) {
                const float cc = fabsf(g00[reg] * irA * ic0) - 0.1f;
                if (cc > 0.f) contrib += cc;
            }
            if (c1ok) {
                const float cc = fabsf(g01[reg] * irA * ic1) - 0.1f;
                if (cc > 0.f) contrib += cc;
            }
            const int rB = 16 + quad * 4 + reg;
            if (rB < 23) {
                const float irB = sInv[rB];
                {
                    const float cc = fabsf(g10[reg] * irB * ic0) - 0.1f;
                    if (cc > 0.f) contrib += cc;
                }
                if (c1ok && rB != 16 + frow) {
                    const float cc = fabsf(g11[reg] * irB * ic1) - 0.1f;
                    if (cc > 0.f) contrib += cc;
                }
            }
        }
#pragma unroll
        for (int m = 32; m; m >>= 1) contrib += __shfl_xor(contrib, m);
        if (lane == 0) atomicAdd(lossAcc, contrib);
    } else {
        // logits: labels 0..23 via 8 lanes/label on waves 1-3; label 24 on wave 1
        const int li = t - 64;
        {
            const int L = li >> 3, chunk = li & 7;
            float a = 0.f;
#pragma unroll
            for (int q4 = 0; q4 < 4; ++q4) {
                const int c8 = chunk * 4 + q4;
                float wf[8]; unp8(*(const uint4*)(Wpb + (size_t)L * 256 + c8 * 8), wf);
                const float4 p0 = *(const float4*)(sPool + c8 * 8);
                const float4 p1 = *(const float4*)(sPool + c8 * 8 + 4);
                a += wf[0] * p0.x + wf[1] * p0.y + wf[2] * p0.z + wf[3] * p0.w
                   + wf[4] * p1.x + wf[5] * p1.y + wf[6] * p1.z + wf[7] * p1.w;
            }
            a += __shfl_xor(a, 1); a += __shfl_xor(a, 2); a += __shfl_xor(a, 4);
            if (chunk == 0) out[1 + b * 25 + L] = a + bp[L];
        }
        if (li < 8) {
            float a = 0.f;
#pragma unroll
            for (int q4 = 0; q4 < 4; ++q4) {
                const int c8 = li * 4 + q4;
                float wf[8]; unp8(*(const uint4*)(Wpb + (size_t)24 * 256 + c8 * 8), wf);
                const float4 p0 = *(const float4*)(sPool + c8 * 8);
                const float4 p1 = *(const float4*)(sPool + c8 * 8 + 4);
                a += wf[0] * p0.x + wf[1] * p0.y + wf[2] * p0.z + wf[3] * p0.w
                   + wf[4] * p1.x + wf[5] * p1.y + wf[6] * p1.z + wf[7] * p1.w;
            }
            a += __shfl_xor(a, 1); a += __shfl_xor(a, 2); a += __shfl_xor(a, 4);
            if (li == 0) out[1 + b * 25 + 24] = a + bp[24];
        }
    }
}

__global__ void loss_finalize(const float* __restrict__ lossAcc, float* __restrict__ out)
{
    out[0] = lossAcc[0] * (1.f / 1036288.f);   // B*S*(S-1) = 2048*23*22
}

// ---------------------------------------------------------------------------
extern "C" void kernel_launch(void* const* d_in, const int* in_sizes, int n_in,
                              void* d_out, int out_size, void* d_ws, size_t ws_size,
                              hipStream_t stream)
{
    const float* cls     = (const float*)d_in[0];
    const int*   mask    = (const int*)d_in[1];
    const float* missing = (const float*)d_in[2];
    const float* W1 = (const float*)d_in[3];  const float* b1 = (const float*)d_in[4];
    const float* W2 = (const float*)d_in[5];  const float* b2 = (const float*)d_in[6];
    const float* lng = (const float*)d_in[7]; const float* lnb = (const float*)d_in[8];
    const float* Wq = (const float*)d_in[9];  const float* bq = (const float*)d_in[10];
    const float* Wk = (const float*)d_in[11]; const float* bk = (const float*)d_in[12];
    const float* Wv = (const float*)d_in[13]; const float* bv = (const float*)d_in[14];
    const float* Wo = (const float*)d_in[15]; const float* bo = (const float*)d_in[16];
    const float* Wp = (const float*)d_in[17]; const float* bp = (const float*)d_in[18];
    float* out = (float*)d_out;

    char* ws = (char*)d_ws;
    u16* h1b  = (u16*)ws;                         // [CAPROWS][384] compact
    u16* redb = (u16*)(ws + 35487744);            // [CAPROWS][256] compact h2
    u16* Wb   = (u16*)(ws + 59146240);            // bf16 weights (661,760 elems)
    u16* W1b   = Wb;
    u16* W2b   = Wb + 294912;
    u16* Wqkvb = Wb + 393216;                     // q,k,v contiguous [768][256]
    u16* Wob   = Wb + 589824;
    u16* Wpb   = Wb + 655360;
    int* idx    = (int*)(ws + 60469760);          // [47104]
    int* rowsrc = (int*)(ws + 60658176);          // [CAPROWS]
    int* cnt    = (int*)(ws + 60843008);
    float* lossAcc = (float*)(ws + 60843012);

    // cnt + lossAcc are adjacent -> one 8-byte clear
    hipMemsetAsync(cnt, 0, 8, stream);
    hipMemsetAsync(rowsrc, 0, CAPROWS * sizeof(int), stream);

    // weight conversion + fused row-compaction scan
    wconv<<<2585, 256, 0, stream>>>(W1, W2, Wq, Wk, Wv, Wo, Wp, Wb,
                                    mask, idx, rowsrc, cnt);
    // h1[slot] = gelu(srcrow @ W1^T + b1)  (compact rows only)
    gemm1_kernel<<<dim3(3, 361), 256, 0, stream>>>(cls, rowsrc, cnt, missing,
                                                   W1b, b1, h1b);
    // h2[slot] = gelu(h1 @ W2^T + b2) -> redb (pre-LN; LN fused into attn_tail)
    gemm_bt<<<dim3(2, 361), 256, 0, stream>>>(h1b, W2b, b2, redb, 384, 256, cnt);
    // fused: LN + QKV + attention + Wo + updated + gram loss + pool + logits
    attn_tail_kernel<<<2048, 256, 0, stream>>>(redb, mask, idx, Wqkvb, bq, bk, bv,
                                               Wob, bo, lng, lnb, Wpb, bp,
                                               out, lossAcc);
    loss_finalize<<<1, 1, 0, stream>>>(lossAcc, out);
}